// Round 1
// baseline (329.501 us; speedup 1.0000x reference)
//
#include <hip/hip_runtime.h>

// InstantNGP hash-grid forward, fp32.
// Per-level constants (host-derived, see reference _level_consts()):
//   res   = 16 << l          (grid resolution)
//   scale = res - 1          (exact in fp32)
//   size  = 1 << min(12+3l, 19)   -> mask = size-1
//   strides = [1, res, (l<=5 ? res*res : 0)]   (uint32 wrap reproduces ref)
//   use_hash: levels 3..11 only (12..15 wrap stride to 0 -> linear path!)

static constexpr int N_PTS = 500000;

__global__ __launch_bounds__(256) void hashgrid_fwd(
    const float* __restrict__ coords,   // [N,3]
    const float* __restrict__ table,    // [T,4] (only rows < 2^19 ever touched)
    float* __restrict__ out)            // [N,64]
{
    const unsigned t = blockIdx.x * 256u + threadIdx.x;
    const unsigned n = t >> 4;    // point
    const unsigned l = t & 15u;   // level
    if (n >= (unsigned)N_PTS) return;

    const float cx = coords[n * 3 + 0];
    const float cy = coords[n * 3 + 1];
    const float cz = coords[n * 3 + 2];

    const unsigned res = 16u << l;
    const float scale = (float)(res - 1u);

    // pos = c*scale + 0.5 with NO fma contraction (match np fp32 rounding so
    // floor() boundaries agree with the reference exactly)
    const float px = __fadd_rn(__fmul_rn(cx, scale), 0.5f);
    const float py = __fadd_rn(__fmul_rn(cy, scale), 0.5f);
    const float pz = __fadd_rn(__fmul_rn(cz, scale), 0.5f);
    const float bxf = floorf(px), byf = floorf(py), bzf = floorf(pz);
    const float fx = __fsub_rn(px, bxf);
    const float fy = __fsub_rn(py, byf);
    const float fz = __fsub_rn(pz, bzf);
    const unsigned x = (unsigned)(int)bxf;   // base >= 0 always (coords in [0,1))
    const unsigned y = (unsigned)(int)byf;
    const unsigned z = (unsigned)(int)bzf;

    const unsigned mask = (l >= 3u) ? 0x7FFFFu : ((1u << (12u + 3u * l)) - 1u);
    const bool hashp = (l >= 3u) && (l <= 11u);

    // corner index c = (dx<<2)|(dy<<1)|dz  (matches CORNERS ordering)
    unsigned slot[8];
    if (hashp) {
        const unsigned hx0 = x,                  hx1 = x + 1u;           // *prime0=1
        const unsigned hy0 = y * 2654435761u,    hy1 = (y + 1u) * 2654435761u;
        const unsigned hz0 = z * 805459861u,     hz1 = (z + 1u) * 805459861u;
        slot[0] = (hx0 ^ hy0 ^ hz0) & mask;
        slot[1] = (hx0 ^ hy0 ^ hz1) & mask;
        slot[2] = (hx0 ^ hy1 ^ hz0) & mask;
        slot[3] = (hx0 ^ hy1 ^ hz1) & mask;
        slot[4] = (hx1 ^ hy0 ^ hz0) & mask;
        slot[5] = (hx1 ^ hy0 ^ hz1) & mask;
        slot[6] = (hx1 ^ hy1 ^ hz0) & mask;
        slot[7] = (hx1 ^ hy1 ^ hz1) & mask;
    } else {
        const unsigned zs = (l <= 5u) ? res * res : 0u;   // stride[2] (0 for l>=6)
        const unsigned b = x + y * res + z * zs;          // uint32 wrap = ref semantics
        slot[0] = (b)                  & mask;
        slot[1] = (b + zs)             & mask;
        slot[2] = (b + res)            & mask;
        slot[3] = (b + res + zs)       & mask;
        slot[4] = (b + 1u)             & mask;
        slot[5] = (b + 1u + zs)        & mask;
        slot[6] = (b + 1u + res)       & mask;
        slot[7] = (b + 1u + res + zs)  & mask;
    }

    // trilinear weights, product order ((wx*wy)*wz) like np.prod over last axis
    const float gx = 1.0f - fx, gy = 1.0f - fy, gz = 1.0f - fz;
    float w[8];
    w[0] = gx * gy * gz;
    w[1] = gx * gy * fz;
    w[2] = gx * fy * gz;
    w[3] = gx * fy * fz;
    w[4] = fx * gy * gz;
    w[5] = fx * gy * fz;
    w[6] = fx * fy * gz;
    w[7] = fx * fy * fz;

    float a0 = 0.f, a1 = 0.f, a2 = 0.f, a3 = 0.f;
    #pragma unroll
    for (int c = 0; c < 8; ++c) {
        const float4 e = *(const float4*)(table + (size_t)slot[c] * 4u);
        a0 = fmaf(w[c], e.x, a0);
        a1 = fmaf(w[c], e.y, a1);
        a2 = fmaf(w[c], e.z, a2);
        a3 = fmaf(w[c], e.w, a3);
    }

    // lanes 0..15 cover one point's 64 floats -> wave store = 1 KiB contiguous
    float4 o = make_float4(a0, a1, a2, a3);
    *(float4*)(out + (size_t)n * 64u + (size_t)l * 4u) = o;
}

extern "C" void kernel_launch(void* const* d_in, const int* in_sizes, int n_in,
                              void* d_out, int out_size, void* d_ws, size_t ws_size,
                              hipStream_t stream) {
    const float* coords = (const float*)d_in[0];
    const float* table  = (const float*)d_in[1];
    float* out = (float*)d_out;

    const int n = in_sizes[0] / 3;                // 500000
    const int total = n * 16;                     // one thread per (point, level)
    const int blocks = (total + 255) / 256;       // 31250
    hipLaunchKernelGGL(hashgrid_fwd, dim3(blocks), dim3(256), 0, stream,
                       coords, table, out);
}